// Round 2
// baseline (65.773 us; speedup 1.0000x reference)
//
#include <hip/hip_runtime.h>

// Problem: B=8, N=50, T=64, H=32  ->  BN = 400 independent "graphs". All f32.
//
// Algebraic collapse of the reference:
//   adj[b,i,j] = s_send[b,i] + s_rec[b,j] + bias   (one-hot rel matrices)
//   softmax over j kills every i-dependent shift -> p[b,j] = softmax_j(w_rec . hs[b,j])
//   cs[b,i,:] = sum_j p[b,j] * hs[b,j,:]           (same vector for every i)
// rel_rec_t / rel_send_t / soft_att_b are dead inputs.

#define TT 64   // timesteps (== wave size)
#define HH 32   // hidden

__global__ __launch_bounds__(256) void soft_att_kernel(
    const float* __restrict__ x,   // [BN, T, H] f32
    const float* __restrict__ w,   // [2H] f32 (receiver half used: w[32..63])
    float* __restrict__ out,       // [BN, T, H] f32
    int nbn)
{
    const int wave = threadIdx.x >> 6;
    const int j    = threadIdx.x & 63;          // lane == timestep
    const int bn   = blockIdx.x * 4 + wave;
    if (bn >= nbn) return;
    const size_t rowoff = ((size_t)bn * TT + j) * HH;

    // ---- lane j loads its timestep row: 32 f32 = 128 B (wave: contiguous 8 KB) ----
    float xv[HH];
    {
        const float4* rp = (const float4*)(x + rowoff);
        #pragma unroll
        for (int c = 0; c < 8; ++c) {
            float4 q = rp[c];
            xv[4 * c + 0] = q.x; xv[4 * c + 1] = q.y;
            xv[4 * c + 2] = q.z; xv[4 * c + 3] = q.w;
        }
    }

    // ---- s_rec[j] = x_j . w_rec  (w wave-uniform -> scalar loads) ----
    float s = 0.f;
    #pragma unroll
    for (int h = 0; h < HH; ++h) s = fmaf(xv[h], w[HH + h], s);

    // ---- 64-lane softmax over timesteps ----
    float m = s;
    #pragma unroll
    for (int off = 32; off; off >>= 1) m = fmaxf(m, __shfl_xor(m, off, 64));
    float e = __expf(s - m);
    float sum = e;
    #pragma unroll
    for (int off = 32; off; off >>= 1) sum += __shfl_xor(sum, off, 64);
    const float p = e / sum;

    // ---- o[h] = sum_j p_j * x_j[h]; butterfly so every lane ends with o ----
    float v[HH];
    #pragma unroll
    for (int h = 0; h < HH; ++h) v[h] = p * xv[h];
    #pragma unroll
    for (int off = 32; off; off >>= 1) {
        #pragma unroll
        for (int h = 0; h < HH; ++h) v[h] += __shfl_xor(v[h], off, 64);
    }

    // ---- lane j writes row t=j (all rows identical; coalesced 8 KB store) ----
    float4* outp = (float4*)(out + rowoff);
    #pragma unroll
    for (int c = 0; c < 8; ++c)
        outp[c] = make_float4(v[4 * c + 0], v[4 * c + 1],
                              v[4 * c + 2], v[4 * c + 3]);
}

extern "C" void kernel_launch(void* const* d_in, const int* in_sizes, int n_in,
                              void* d_out, int out_size, void* d_ws, size_t ws_size,
                              hipStream_t stream) {
    // setup_inputs order: inputs[0], rel_rec_t[1], rel_send_t[2], soft_att_w[3], soft_att_b[4]
    const float* x = (const float*)d_in[0];
    const float* w = (const float*)d_in[3];
    float* out     = (float*)d_out;
    const int nbn  = in_sizes[0] / (TT * HH);   // 400
    const int blocks = (nbn + 3) / 4;           // 4 waves (bn) per 256-thread block
    soft_att_kernel<<<blocks, 256, 0, stream>>>(x, w, out, nbn);
}